// Round 4
// baseline (628.444 us; speedup 1.0000x reference)
//
#include <hip/hip_runtime.h>
#include <hip/hip_bf16.h>

#define NN    65536
#define KDIM  1024
#define HDIM  256
#define NC    8
#define BM    64
#define NKB2  32      // number of 32-wide K blocks

typedef __bf16 bf16x8 __attribute__((ext_vector_type(8)));
typedef float  f32x4  __attribute__((ext_vector_type(4)));
typedef __attribute__((address_space(1))) void GV;
typedef __attribute__((address_space(3))) void LV;

static __device__ __forceinline__ void async_cp16(const void* g, void* l) {
    __builtin_amdgcn_global_load_lds((GV*)g, (LV*)l, 16, 0, 0);
}

// s_waitcnt vmcnt(8), lgkmcnt=no-wait(15), expcnt=no-wait(7): gfx9 imm encoding
#define WAIT_VM8() __builtin_amdgcn_s_waitcnt(0x0F78)

static __device__ __forceinline__ unsigned short f2bf_rne(float f) {
    unsigned int u = __float_as_uint(f);
    unsigned int r = u + 0x7fffu + ((u >> 16) & 1u);
    return (unsigned short)(r >> 16);
}

static __device__ __forceinline__ unsigned long long pack4bf(float4 v) {
    return (unsigned long long)f2bf_rne(v.x)
         | ((unsigned long long)f2bf_rne(v.y) << 16)
         | ((unsigned long long)f2bf_rne(v.z) << 32)
         | ((unsigned long long)f2bf_rne(v.w) << 48);
}

static __device__ __forceinline__ bf16x8 cvt8(float4 a, float4 b) {
    __hip_bfloat162 p0 = __float22bfloat162_rn(float2{a.x, a.y});
    __hip_bfloat162 p1 = __float22bfloat162_rn(float2{a.z, a.w});
    __hip_bfloat162 p2 = __float22bfloat162_rn(float2{b.x, b.y});
    __hip_bfloat162 p3 = __float22bfloat162_rn(float2{b.z, b.w});
    union { __hip_bfloat162 h[4]; bf16x8 v; } u;
    u.h[0] = p0; u.h[1] = p1; u.h[2] = p2; u.h[3] = p3;
    return u.v;
}

// ---- Kernel 1: W1 fp32 -> bf16 in BK=32 tile order, + per-block cid hist ---
// W1b flat chunk index (chunk = 8 bf16 = 16 B): kb2*1024 + n*4 + kc
// holds W1[n][kb2*32 + kc*8 .. +7]
__global__ __launch_bounds__(256) void prep_kernel(
    const float* __restrict__ W1, unsigned short* __restrict__ W1b,
    const int* __restrict__ cid, int* __restrict__ cnt_partial)
{
    __shared__ int hcnt[NC];
    if (threadIdx.x < NC) hcnt[threadIdx.x] = 0;
    __syncthreads();

    const int gid = blockIdx.x * 256 + threadIdx.x;   // 0..32767 chunks
    const int kc  = gid & 3;
    const int n   = (gid >> 2) & 255;
    const int kb2 = gid >> 10;
    const float* src = W1 + (size_t)n * KDIM + kb2 * 32 + kc * 8;
    float4 v0 = *(const float4*)(src);
    float4 v1 = *(const float4*)(src + 4);
    ulonglong2 pk;
    pk.x = pack4bf(v0);
    pk.y = pack4bf(v1);
    *(ulonglong2*)(W1b + (size_t)gid * 8) = pk;

    atomicAdd(&hcnt[cid[gid]], 1);                    // LDS atomics only
    atomicAdd(&hcnt[cid[gid + 32768]], 1);
    __syncthreads();
    if (threadIdx.x < NC)
        cnt_partial[blockIdx.x * NC + threadIdx.x] = hcnt[threadIdx.x];
}

// ---- Kernel 2: bf16 MFMA GEMM + ReLU + per-cluster per-block segment sum --
// Pipeline: raw s_barrier + manual vmcnt(8) so the 8 x-prefetch loads stay in
// flight across the barrier; W1 async->LDS double-buffered; x fragments loaded
// directly global->reg (no LDS round-trip).
__global__ __launch_bounds__(256, 3) void gemm_kernel(
    const float* __restrict__ x, const int* __restrict__ cid,
    const unsigned short* __restrict__ W1b, const float* __restrict__ b1,
    float* __restrict__ partial)
{
    __shared__ __align__(16) unsigned short wsb[2][1024 * 8];   // 2 x 16 KB
    __shared__ float lsums[HDIM * NC];                          // 8 KB, [col][k]
    __shared__ int cids[BM];

    const int tid  = threadIdx.x;
    const int wave = tid >> 6;
    const int lane = tid & 63;
    const int l15  = lane & 15;
    const int q    = lane >> 4;
    const int row0 = blockIdx.x * BM;

    for (int i = tid; i < HDIM * NC; i += 256) lsums[i] = 0.0f;
    if (tid < BM) cids[tid] = cid[row0 + tid];
    __syncthreads();   // lsums/cids visible before the raw-barrier loop

    f32x4 acc[4][4];
    #pragma unroll
    for (int i = 0; i < 4; ++i)
        #pragma unroll
        for (int j = 0; j < 4; ++j)
            #pragma unroll
            for (int r = 0; r < 4; ++r) acc[i][j][r] = 0.0f;

    // W1 async: wave covers chunks [wave*256, wave*256+256) of each kb-tile
    const unsigned short* wgl = W1b + (size_t)(wave * 256 + lane) * 8;

    // x fragment bases: lane (l15,q) owns x[row0 + i*16 + l15][q*8 ..]
    const float* xb0 = x + (size_t)(row0 + 0 * 16 + l15) * KDIM + q * 8;
    const float* xb1 = x + (size_t)(row0 + 1 * 16 + l15) * KDIM + q * 8;
    const float* xb2 = x + (size_t)(row0 + 2 * 16 + l15) * KDIM + q * 8;
    const float* xb3 = x + (size_t)(row0 + 3 * 16 + l15) * KDIM + q * 8;

    float4 xf[8];

    // ---- prologue: stage kb=0 ----
    {
        unsigned short* wl = (unsigned short*)&wsb[0][0] + wave * 2048;
        #pragma unroll
        for (int t = 0; t < 4; ++t)
            async_cp16(wgl + t * 512, wl + t * 512);
        xf[0] = *(const float4*)(xb0);  xf[1] = *(const float4*)(xb0 + 4);
        xf[2] = *(const float4*)(xb1);  xf[3] = *(const float4*)(xb1 + 4);
        xf[4] = *(const float4*)(xb2);  xf[5] = *(const float4*)(xb2 + 4);
        xf[6] = *(const float4*)(xb3);  xf[7] = *(const float4*)(xb3 + 4);
        WAIT_VM8();                      // asyncs done; x loads remain in flight
        __builtin_amdgcn_s_barrier();
    }

    for (int kb = 0; kb < NKB2; ++kb) {
        const int cur = kb & 1;

        // convert this iter's x fragments (compiler waits only the 8 oldest loads)
        bf16x8 af[4];
        af[0] = cvt8(xf[0], xf[1]);
        af[1] = cvt8(xf[2], xf[3]);
        af[2] = cvt8(xf[4], xf[5]);
        af[3] = cvt8(xf[6], xf[7]);

        if (kb + 1 < NKB2) {
            // asyncs FIRST (so vmcnt(8) at the tail drains them, not the x loads)
            unsigned short* wl = (unsigned short*)&wsb[cur ^ 1][0] + wave * 2048;
            const unsigned short* wg = wgl + (size_t)(kb + 1) * 8192;
            #pragma unroll
            for (int t = 0; t < 4; ++t)
                async_cp16(wg + t * 512, wl + t * 512);
            // then x prefetch for kb+1 (advance bases by 32 floats)
            xb0 += 32; xb1 += 32; xb2 += 32; xb3 += 32;
            xf[0] = *(const float4*)(xb0);  xf[1] = *(const float4*)(xb0 + 4);
            xf[2] = *(const float4*)(xb1);  xf[3] = *(const float4*)(xb1 + 4);
            xf[4] = *(const float4*)(xb2);  xf[5] = *(const float4*)(xb2 + 4);
            xf[6] = *(const float4*)(xb3);  xf[7] = *(const float4*)(xb3 + 4);
        }

        bf16x8 bfr[4];
        #pragma unroll
        for (int j = 0; j < 4; ++j)
            bfr[j] = *(const bf16x8*)&wsb[cur][((wave * 64 + j * 16 + l15) * 4 + q) * 8];

        #pragma unroll
        for (int i = 0; i < 4; ++i)
            #pragma unroll
            for (int j = 0; j < 4; ++j)
                acc[i][j] = __builtin_amdgcn_mfma_f32_16x16x32_bf16(af[i], bfr[j], acc[i][j], 0, 0, 0);

        if (kb + 1 < NKB2) {
            WAIT_VM8();                  // drain only the 4 asyncs; x stays in flight
            __builtin_amdgcn_s_barrier();
        }
    }

    // epilogue: bias + relu + per-cluster LDS accumulation ([col][k] layout)
    float b1v[4];
    #pragma unroll
    for (int j = 0; j < 4; ++j) b1v[j] = b1[wave * 64 + j * 16 + l15];

    #pragma unroll
    for (int i = 0; i < 4; ++i) {
        #pragma unroll
        for (int j = 0; j < 4; ++j) {
            const int col = wave * 64 + j * 16 + l15;
            #pragma unroll
            for (int r = 0; r < 4; ++r) {
                float v = fmaxf(acc[i][j][r] + b1v[j], 0.0f);
                int m = i * 16 + q * 4 + r;
                atomicAdd(&lsums[col * NC + cids[m]], v);
            }
        }
    }
    __syncthreads();
    // plain coalesced store of this block's partial sums (no global atomics)
    float* dst = partial + (size_t)blockIdx.x * 2048 + tid * 8;
    *(f32x4*)dst       = *(const f32x4*)&lsums[tid * 8];
    *(f32x4*)(dst + 4) = *(const f32x4*)&lsums[tid * 8 + 4];
}

// ---- Kernel 3: reduce 1024 partials -> stage2[8][2048] (no atomics) -------
__global__ __launch_bounds__(256) void reduce_kernel(
    const float* __restrict__ partial, float* __restrict__ stage2)
{
    const int s  = blockIdx.x >> 3;   // pb-split 0..7 (128 blocks each)
    const int og = blockIdx.x & 7;    // output group
    const int o  = og * 256 + threadIdx.x;
    const float* p = partial + (size_t)s * 128 * 2048 + o;
    float a0=0,a1=0,a2=0,a3=0,a4=0,a5=0,a6=0,a7=0;
    #pragma unroll 4
    for (int pb = 0; pb < 128; pb += 8) {
        a0 += p[(size_t)(pb+0)*2048]; a1 += p[(size_t)(pb+1)*2048];
        a2 += p[(size_t)(pb+2)*2048]; a3 += p[(size_t)(pb+3)*2048];
        a4 += p[(size_t)(pb+4)*2048]; a5 += p[(size_t)(pb+5)*2048];
        a6 += p[(size_t)(pb+6)*2048]; a7 += p[(size_t)(pb+7)*2048];
    }
    stage2[(size_t)s * 2048 + o] = ((a0+a1)+(a2+a3)) + ((a4+a5)+(a6+a7));
}

// ---- Kernel 4: fused head: counts+mean -> Linear+ReLU -> gated attn -------
__global__ __launch_bounds__(256) void head_kernel(
    const float* __restrict__ stage2, const int* __restrict__ cnt_partial,
    const float* __restrict__ Wf, const float* __restrict__ bf1,
    const float* __restrict__ Wa, const float* __restrict__ ba,
    const float* __restrict__ Wb, const float* __restrict__ bb,
    const float* __restrict__ Wc, const float* __restrict__ bc,
    float* __restrict__ out)
{
    __shared__ float hcT[HDIM * NC];  // [d][k]
    __shared__ float hpT[HDIM * NC];  // [d][k]
    __shared__ float red[NC * 4];
    __shared__ int   cnt_s[256];
    __shared__ float cnt_f[NC];
    const int c = threadIdx.x;
    const int wave = c >> 6, lane = c & 63;

    // reduce counts: 128 blocks x 8 -> 8
    {
        int k = c & 7, g = c >> 3;                     // g 0..31
        const int* cp = cnt_partial + g * 32 + k;      // 4 blocks of 8
        cnt_s[c] = cp[0] + cp[8] + cp[16] + cp[24];
    }
    __syncthreads();
    if (c < NC) {
        int s = 0;
        #pragma unroll
        for (int g = 0; g < 32; ++g) s += cnt_s[g * 8 + c];
        cnt_f[c] = 1.0f / fmaxf((float)s, 1.0f);
    }
    __syncthreads();

    // final gsum reduce (8 stage2 slices) + mean
    {
        float a[NC] = {0,0,0,0,0,0,0,0};
        #pragma unroll
        for (int s = 0; s < 8; ++s) {
            f32x4 u0 = *(const f32x4*)&stage2[(size_t)s * 2048 + c * 8];
            f32x4 u1 = *(const f32x4*)&stage2[(size_t)s * 2048 + c * 8 + 4];
            a[0]+=u0[0]; a[1]+=u0[1]; a[2]+=u0[2]; a[3]+=u0[3];
            a[4]+=u1[0]; a[5]+=u1[1]; a[6]+=u1[2]; a[7]+=u1[3];
        }
        #pragma unroll
        for (int k = 0; k < NC; ++k) hcT[c * NC + k] = a[k] * cnt_f[k];
    }
    __syncthreads();

    // h_path[k][c] = relu(Wf[c,:] . hc[k,:] + bf[c])
    {
        float acc[NC];
        float bias = bf1[c];
        #pragma unroll
        for (int k = 0; k < NC; ++k) acc[k] = bias;
        const float4* wf4 = (const float4*)(Wf + (size_t)c * HDIM);
        for (int d4 = 0; d4 < 64; ++d4) {
            float4 w = wf4[d4];
            #pragma unroll
            for (int e = 0; e < 4; ++e) {
                float wd = (e == 0) ? w.x : (e == 1) ? w.y : (e == 2) ? w.z : w.w;
                const f32x4 h0 = *(const f32x4*)&hcT[(d4 * 4 + e) * NC];
                const f32x4 h1 = *(const f32x4*)&hcT[(d4 * 4 + e) * NC + 4];
                acc[0] += wd * h0[0]; acc[1] += wd * h0[1];
                acc[2] += wd * h0[2]; acc[3] += wd * h0[3];
                acc[4] += wd * h1[0]; acc[5] += wd * h1[1];
                acc[6] += wd * h1[2]; acc[7] += wd * h1[3];
            }
        }
        #pragma unroll
        for (int k = 0; k < NC; ++k) hpT[c * NC + k] = fmaxf(acc[k], 0.0f);
    }
    __syncthreads();

    // gated attention logits
    float za[NC], zb[NC];
    {
        float biasa = ba[c], biasb = bb[c];
        #pragma unroll
        for (int k = 0; k < NC; ++k) { za[k] = biasa; zb[k] = biasb; }
        const float4* wa4 = (const float4*)(Wa + (size_t)c * HDIM);
        const float4* wb4 = (const float4*)(Wb + (size_t)c * HDIM);
        for (int d4 = 0; d4 < 64; ++d4) {
            float4 wa = wa4[d4], wb = wb4[d4];
            #pragma unroll
            for (int e = 0; e < 4; ++e) {
                float wav = (e == 0) ? wa.x : (e == 1) ? wa.y : (e == 2) ? wa.z : wa.w;
                float wbv = (e == 0) ? wb.x : (e == 1) ? wb.y : (e == 2) ? wb.z : wb.w;
                const f32x4 h0 = *(const f32x4*)&hpT[(d4 * 4 + e) * NC];
                const f32x4 h1 = *(const f32x4*)&hpT[(d4 * 4 + e) * NC + 4];
                za[0] += wav * h0[0]; za[1] += wav * h0[1]; za[2] += wav * h0[2]; za[3] += wav * h0[3];
                za[4] += wav * h1[0]; za[5] += wav * h1[1]; za[6] += wav * h1[2]; za[7] += wav * h1[3];
                zb[0] += wbv * h0[0]; zb[1] += wbv * h0[1]; zb[2] += wbv * h0[2]; zb[3] += wbv * h0[3];
                zb[4] += wbv * h1[0]; zb[5] += wbv * h1[1]; zb[6] += wbv * h1[2]; zb[7] += wbv * h1[3];
            }
        }
    }
    float wcv = Wc[c];
    float v[NC];
    #pragma unroll
    for (int k = 0; k < NC; ++k) {
        float a = tanhf(za[k]);
        float g = 1.0f / (1.0f + expf(-zb[k]));
        v[k] = a * g * wcv;
    }
    #pragma unroll
    for (int k = 0; k < NC; ++k) {
        float s = v[k];
        #pragma unroll
        for (int off = 32; off > 0; off >>= 1) s += __shfl_down(s, off, 64);
        if (lane == 0) red[k * 4 + wave] = s;
    }
    __syncthreads();
    float logit[NC], m = -1e30f;
    #pragma unroll
    for (int k = 0; k < NC; ++k) {
        logit[k] = red[k * 4] + red[k * 4 + 1] + red[k * 4 + 2] + red[k * 4 + 3] + bc[0];
        m = fmaxf(m, logit[k]);
    }
    float s = 0.0f, ex[NC];
    #pragma unroll
    for (int k = 0; k < NC; ++k) { ex[k] = expf(logit[k] - m); s += ex[k]; }
    float inv = 1.0f / s;
    float o = 0.0f;
    #pragma unroll
    for (int k = 0; k < NC; ++k) o += ex[k] * inv * hpT[c * NC + k];
    out[c] = o;
}

extern "C" void kernel_launch(void* const* d_in, const int* in_sizes, int n_in,
                              void* d_out, int out_size, void* d_ws, size_t ws_size,
                              hipStream_t stream)
{
    (void)in_sizes; (void)n_in; (void)out_size; (void)ws_size;
    const float* x   = (const float*)d_in[0];
    const int*   cid = (const int*)  d_in[1];
    const float* W1  = (const float*)d_in[2];
    const float* b1  = (const float*)d_in[3];
    const float* Wf  = (const float*)d_in[4];
    const float* bfv = (const float*)d_in[5];
    const float* Wa  = (const float*)d_in[6];
    const float* ba  = (const float*)d_in[7];
    const float* Wb  = (const float*)d_in[8];
    const float* bb  = (const float*)d_in[9];
    const float* Wc  = (const float*)d_in[10];
    const float* bc  = (const float*)d_in[11];
    float* out = (float*)d_out;

    // workspace layout (~9.0 MB, no zero-init required anywhere)
    unsigned short* W1b   = (unsigned short*)d_ws;                     // 512 KB
    int*   cnt_partial    = (int*)  ((char*)d_ws + 524288);            // 4 KB
    float* partial        = (float*)((char*)d_ws + 528384);            // 8 MB
    float* stage2         = (float*)((char*)d_ws + 528384 + 8388608);  // 64 KB

    hipLaunchKernelGGL(prep_kernel,   dim3(128),     dim3(256), 0, stream, W1, W1b, cid, cnt_partial);
    hipLaunchKernelGGL(gemm_kernel,   dim3(NN / BM), dim3(256), 0, stream, x, cid, W1b, b1, partial);
    hipLaunchKernelGGL(reduce_kernel, dim3(64),      dim3(256), 0, stream, partial, stage2);
    hipLaunchKernelGGL(head_kernel,   dim3(1),       dim3(256), 0, stream,
                       stage2, cnt_partial, Wf, bfv, Wa, ba, Wb, bb, Wc, bc, out);
}

// Round 5
// 524.304 us; speedup vs baseline: 1.1986x; 1.1986x over previous
//
#include <hip/hip_runtime.h>
#include <hip/hip_bf16.h>

#define NN    65536
#define KDIM  1024
#define HDIM  256
#define NC    8
#define BM    64
#define NPH   32      // K phases of 32

typedef __bf16 bf16x8 __attribute__((ext_vector_type(8)));
typedef float  f32x4  __attribute__((ext_vector_type(4)));
typedef __attribute__((address_space(1))) void GV;
typedef __attribute__((address_space(3))) void LV;

static __device__ __forceinline__ void async_cp16(const void* g, void* l) {
    __builtin_amdgcn_global_load_lds((GV*)g, (LV*)l, 16, 0, 0);
}

// s_waitcnt immediates (gfx9): vmcnt low[3:0]|hi[15:14], expcnt[6:4], lgkmcnt[11:8]
#define WAIT_VM6()        __builtin_amdgcn_s_waitcnt(0x0F76)  // vmcnt(6), lgkm/exp no-wait
#define WAIT_VM4()        __builtin_amdgcn_s_waitcnt(0x0F74)  // vmcnt(4)
#define WAIT_VM6_LGKM0()  __builtin_amdgcn_s_waitcnt(0x0076)  // vmcnt(6) + lgkmcnt(0)
#define SCHED_PIN()       __builtin_amdgcn_sched_barrier(0)

static __device__ __forceinline__ unsigned short f2bf_rne(float f) {
    unsigned int u = __float_as_uint(f);
    unsigned int r = u + 0x7fffu + ((u >> 16) & 1u);
    return (unsigned short)(r >> 16);
}

static __device__ __forceinline__ unsigned long long pack4bf(float4 v) {
    return (unsigned long long)f2bf_rne(v.x)
         | ((unsigned long long)f2bf_rne(v.y) << 16)
         | ((unsigned long long)f2bf_rne(v.z) << 32)
         | ((unsigned long long)f2bf_rne(v.w) << 48);
}

static __device__ __forceinline__ bf16x8 cvt8(f32x4 a, f32x4 b) {
    __hip_bfloat162 p0 = __float22bfloat162_rn(float2{a[0], a[1]});
    __hip_bfloat162 p1 = __float22bfloat162_rn(float2{a[2], a[3]});
    __hip_bfloat162 p2 = __float22bfloat162_rn(float2{b[0], b[1]});
    __hip_bfloat162 p3 = __float22bfloat162_rn(float2{b[2], b[3]});
    union { __hip_bfloat162 h[4]; bf16x8 v; } u;
    u.h[0] = p0; u.h[1] = p1; u.h[2] = p2; u.h[3] = p3;
    return u.v;
}

// ---- Kernel 1: W1 fp32 -> bf16, B-fragment-linear layout + per-block hist --
// chunk index ci = ((kb*4 + wave)*4 + j)*64 + lane  (chunk = 8 bf16 = 16 B)
// content: W1[n][k0..k0+7], n = wave*64 + j*16 + (lane&15), k0 = kb*32 + (lane>>4)*8
__global__ __launch_bounds__(256) void prep_kernel(
    const float* __restrict__ W1, unsigned short* __restrict__ W1b,
    const int* __restrict__ cid, int* __restrict__ cnt_partial)
{
    __shared__ int hcnt[NC];
    if (threadIdx.x < NC) hcnt[threadIdx.x] = 0;
    __syncthreads();

    const int gid  = blockIdx.x * 256 + threadIdx.x;   // 0..32767 chunks
    const int lane = gid & 63;
    const int j    = (gid >> 6) & 3;
    const int wv   = (gid >> 8) & 3;
    const int kb   = gid >> 10;
    const int n    = wv * 64 + j * 16 + (lane & 15);
    const int k0   = kb * 32 + (lane >> 4) * 8;
    const float* src = W1 + (size_t)n * KDIM + k0;
    float4 v0 = *(const float4*)(src);
    float4 v1 = *(const float4*)(src + 4);
    ulonglong2 pk;
    pk.x = pack4bf(v0);
    pk.y = pack4bf(v1);
    *(ulonglong2*)(W1b + (size_t)gid * 8) = pk;

    atomicAdd(&hcnt[cid[gid]], 1);                    // LDS atomics only
    atomicAdd(&hcnt[cid[gid + 32768]], 1);
    __syncthreads();
    if (threadIdx.x < NC)
        cnt_partial[blockIdx.x * NC + threadIdx.x] = hcnt[threadIdx.x];
}

// ---- Kernel 2: bf16 MFMA GEMM + ReLU + per-cluster per-block segment sum --
// x: async global->LDS (fp32, XOR-swizzled), 3-buffer ring, 2 phases ahead.
// W1: global->reg (L2-resident), 1 phase ahead. Raw barrier + vmcnt(6).
__global__ __launch_bounds__(256, 4) void gemm_kernel(
    const float* __restrict__ x, const int* __restrict__ cid,
    const unsigned short* __restrict__ W1b, const float* __restrict__ b1,
    float* __restrict__ partial)
{
    __shared__ __align__(16) char xs[3 * 8192];       // 3 x (64 rows x 32k fp32, swizzled)
    __shared__ float lsums[HDIM * NC];                // 8 KB, [col][k]
    __shared__ int cids[BM];

    const int tid  = threadIdx.x;
    const int wave = tid >> 6;
    const int lane = tid & 63;
    const int l15  = lane & 15;
    const int q    = lane >> 4;
    const int row0 = blockIdx.x * BM;

    for (int i = tid; i < HDIM * NC; i += 256) lsums[i] = 0.0f;
    if (tid < BM) cids[tid] = cid[row0 + tid];

    // x async per-lane global base: r_lane = lane>>3, chunk c = (lane&7)^(lane>>3)
    const int rl = lane >> 3;
    const int cl = (lane & 7) ^ rl;
    const float* xg = x + (size_t)(row0 + wave * 16 + rl) * KDIM + cl * 4;
    // per (h, kb): + h*8*KDIM + kb*32.  LDS instr base: wave*2048 + h*1024 (+buf*8192)

    // B per-lane global base (shorts): wave*2048 + lane*8; per (kb,j): + kb*8192 + j*512
    const unsigned short* bg = W1b + (size_t)(wave * 256 + lane) * 8;

    // LDS read offsets for A fragments (bytes): slot=(i*16+l15)*8 + ((2q+e)^(l15&7))
    const int le0 = l15 * 128 + (((2 * q + 0) ^ (l15 & 7)) * 16);
    const int le1 = l15 * 128 + (((2 * q + 1) ^ (l15 & 7)) * 16);

    f32x4 acc[4][4];
    #pragma unroll
    for (int i = 0; i < 4; ++i)
        #pragma unroll
        for (int j = 0; j < 4; ++j)
            #pragma unroll
            for (int r = 0; r < 4; ++r) acc[i][j][r] = 0.0f;

    bf16x8 bA[4], bB[4];

    // ---- prologue: x_0 -> buf0, B_0 -> bA, x_1 -> buf1 ----
    #pragma unroll
    for (int h = 0; h < 2; ++h)
        async_cp16(xg + (size_t)h * 8 * KDIM, &xs[wave * 2048 + h * 1024]);
    #pragma unroll
    for (int j = 0; j < 4; ++j)
        bA[j] = *(const bf16x8*)(bg + j * 512);
    #pragma unroll
    for (int h = 0; h < 2; ++h)
        async_cp16(xg + (size_t)h * 8 * KDIM + 32, &xs[8192 + wave * 2048 + h * 1024]);
    SCHED_PIN();
    WAIT_VM6_LGKM0();     // drain x_0 + lsums/cids ds_writes; keep B_0 + x_1 in flight
    __builtin_amdgcn_s_barrier();
    SCHED_PIN();

    #pragma unroll
    for (int kb = 0; kb < NPH; ++kb) {
        const int buf = kb % 3;
        bf16x8* curB = (kb & 1) ? bB : bA;
        bf16x8* nxtB = (kb & 1) ? bA : bB;

        // prefetch B_{kb+1} (4 dwordx4, L2)
        if (kb + 1 < NPH) {
            #pragma unroll
            for (int j = 0; j < 4; ++j)
                nxtB[j] = *(const bf16x8*)(bg + (size_t)(kb + 1) * 8192 + j * 512);
        }
        // prefetch x_{kb+2} (2 async instrs into ring buffer (kb+2)%3)
        if (kb + 2 < NPH) {
            const int b2 = (kb + 2) % 3;
            #pragma unroll
            for (int h = 0; h < 2; ++h)
                async_cp16(xg + (size_t)h * 8 * KDIM + (kb + 2) * 32,
                           &xs[b2 * 8192 + wave * 2048 + h * 1024]);
        }

        // compute on buf with curB
        bf16x8 af[4];
        #pragma unroll
        for (int i = 0; i < 4; ++i) {
            const f32x4 v0 = *(const f32x4*)&xs[buf * 8192 + i * 2048 + le0];
            const f32x4 v1 = *(const f32x4*)&xs[buf * 8192 + i * 2048 + le1];
            af[i] = cvt8(v0, v1);
        }
        #pragma unroll
        for (int i = 0; i < 4; ++i)
            #pragma unroll
            for (int j = 0; j < 4; ++j)
                acc[i][j] = __builtin_amdgcn_mfma_f32_16x16x32_bf16(af[i], curB[j], acc[i][j], 0, 0, 0);

        // phase-end: drain exactly what's needed next phase, keep prefetches alive
        if (kb < NPH - 2) {
            SCHED_PIN();
            if (kb < NPH - 2 - 1 + 1 && kb + 2 < NPH) WAIT_VM6(); else WAIT_VM4();
            __builtin_amdgcn_s_barrier();
            SCHED_PIN();
        } else if (kb == NPH - 2) {
            SCHED_PIN();
            WAIT_VM4();   // drain x_{31}; keep B_{31}
            __builtin_amdgcn_s_barrier();
            SCHED_PIN();
        }
        // kb == NPH-1: fall through to epilogue
    }

    // epilogue: bias + relu + per-cluster LDS accumulation ([col][k] layout)
    float b1v[4];
    #pragma unroll
    for (int j = 0; j < 4; ++j) b1v[j] = b1[wave * 64 + j * 16 + l15];

    #pragma unroll
    for (int i = 0; i < 4; ++i) {
        #pragma unroll
        for (int j = 0; j < 4; ++j) {
            const int col = wave * 64 + j * 16 + l15;
            #pragma unroll
            for (int r = 0; r < 4; ++r) {
                float v = fmaxf(acc[i][j][r] + b1v[j], 0.0f);
                int m = i * 16 + q * 4 + r;
                atomicAdd(&lsums[col * NC + cids[m]], v);
            }
        }
    }
    __syncthreads();
    // plain coalesced store of this block's partial sums (no global atomics)
    float* dst = partial + (size_t)blockIdx.x * 2048 + tid * 8;
    *(f32x4*)dst       = *(const f32x4*)&lsums[tid * 8];
    *(f32x4*)(dst + 4) = *(const f32x4*)&lsums[tid * 8 + 4];
}

// ---- Kernel 3: reduce 1024 partials -> stage2[8][2048] (no atomics) -------
__global__ __launch_bounds__(256) void reduce_kernel(
    const float* __restrict__ partial, float* __restrict__ stage2)
{
    const int s  = blockIdx.x >> 3;   // pb-split 0..7 (128 blocks each)
    const int og = blockIdx.x & 7;    // output group
    const int o  = og * 256 + threadIdx.x;
    const float* p = partial + (size_t)s * 128 * 2048 + o;
    float a0=0,a1=0,a2=0,a3=0,a4=0,a5=0,a6=0,a7=0;
    #pragma unroll 4
    for (int pb = 0; pb < 128; pb += 8) {
        a0 += p[(size_t)(pb+0)*2048]; a1 += p[(size_t)(pb+1)*2048];
        a2 += p[(size_t)(pb+2)*2048]; a3 += p[(size_t)(pb+3)*2048];
        a4 += p[(size_t)(pb+4)*2048]; a5 += p[(size_t)(pb+5)*2048];
        a6 += p[(size_t)(pb+6)*2048]; a7 += p[(size_t)(pb+7)*2048];
    }
    stage2[(size_t)s * 2048 + o] = ((a0+a1)+(a2+a3)) + ((a4+a5)+(a6+a7));
}

// ---- Kernel 4: fused head: counts+mean -> Linear+ReLU -> gated attn -------
__global__ __launch_bounds__(256) void head_kernel(
    const float* __restrict__ stage2, const int* __restrict__ cnt_partial,
    const float* __restrict__ Wf, const float* __restrict__ bf1,
    const float* __restrict__ Wa, const float* __restrict__ ba,
    const float* __restrict__ Wb, const float* __restrict__ bb,
    const float* __restrict__ Wc, const float* __restrict__ bc,
    float* __restrict__ out)
{
    __shared__ float hcT[HDIM * NC];  // [d][k]
    __shared__ float hpT[HDIM * NC];  // [d][k]
    __shared__ float red[NC * 4];
    __shared__ int   cnt_s[256];
    __shared__ float cnt_f[NC];
    const int c = threadIdx.x;
    const int wave = c >> 6, lane = c & 63;

    // reduce counts: 128 blocks x 8 -> 8
    {
        int k = c & 7, g = c >> 3;                     // g 0..31
        const int* cp = cnt_partial + g * 32 + k;      // 4 blocks of 8
        cnt_s[c] = cp[0] + cp[8] + cp[16] + cp[24];
    }
    __syncthreads();
    if (c < NC) {
        int s = 0;
        #pragma unroll
        for (int g = 0; g < 32; ++g) s += cnt_s[g * 8 + c];
        cnt_f[c] = 1.0f / fmaxf((float)s, 1.0f);
    }
    __syncthreads();

    // final gsum reduce (8 stage2 slices) + mean
    {
        float a[NC] = {0,0,0,0,0,0,0,0};
        #pragma unroll
        for (int s = 0; s < 8; ++s) {
            f32x4 u0 = *(const f32x4*)&stage2[(size_t)s * 2048 + c * 8];
            f32x4 u1 = *(const f32x4*)&stage2[(size_t)s * 2048 + c * 8 + 4];
            a[0]+=u0[0]; a[1]+=u0[1]; a[2]+=u0[2]; a[3]+=u0[3];
            a[4]+=u1[0]; a[5]+=u1[1]; a[6]+=u1[2]; a[7]+=u1[3];
        }
        #pragma unroll
        for (int k = 0; k < NC; ++k) hcT[c * NC + k] = a[k] * cnt_f[k];
    }
    __syncthreads();

    // h_path[k][c] = relu(Wf[c,:] . hc[k,:] + bf[c])
    {
        float acc[NC];
        float bias = bf1[c];
        #pragma unroll
        for (int k = 0; k < NC; ++k) acc[k] = bias;
        const float4* wf4 = (const float4*)(Wf + (size_t)c * HDIM);
        for (int d4 = 0; d4 < 64; ++d4) {
            float4 w = wf4[d4];
            #pragma unroll
            for (int e = 0; e < 4; ++e) {
                float wd = (e == 0) ? w.x : (e == 1) ? w.y : (e == 2) ? w.z : w.w;
                const f32x4 h0 = *(const f32x4*)&hcT[(d4 * 4 + e) * NC];
                const f32x4 h1 = *(const f32x4*)&hcT[(d4 * 4 + e) * NC + 4];
                acc[0] += wd * h0[0]; acc[1] += wd * h0[1];
                acc[2] += wd * h0[2]; acc[3] += wd * h0[3];
                acc[4] += wd * h1[0]; acc[5] += wd * h1[1];
                acc[6] += wd * h1[2]; acc[7] += wd * h1[3];
            }
        }
        #pragma unroll
        for (int k = 0; k < NC; ++k) hpT[c * NC + k] = fmaxf(acc[k], 0.0f);
    }
    __syncthreads();

    // gated attention logits
    float za[NC], zb[NC];
    {
        float biasa = ba[c], biasb = bb[c];
        #pragma unroll
        for (int k = 0; k < NC; ++k) { za[k] = biasa; zb[k] = biasb; }
        const float4* wa4 = (const float4*)(Wa + (size_t)c * HDIM);
        const float4* wb4 = (const float4*)(Wb + (size_t)c * HDIM);
        for (int d4 = 0; d4 < 64; ++d4) {
            float4 wa = wa4[d4], wb = wb4[d4];
            #pragma unroll
            for (int e = 0; e < 4; ++e) {
                float wav = (e == 0) ? wa.x : (e == 1) ? wa.y : (e == 2) ? wa.z : wa.w;
                float wbv = (e == 0) ? wb.x : (e == 1) ? wb.y : (e == 2) ? wb.z : wb.w;
                const f32x4 h0 = *(const f32x4*)&hpT[(d4 * 4 + e) * NC];
                const f32x4 h1 = *(const f32x4*)&hpT[(d4 * 4 + e) * NC + 4];
                za[0] += wav * h0[0]; za[1] += wav * h0[1]; za[2] += wav * h0[2]; za[3] += wav * h0[3];
                za[4] += wav * h1[0]; za[5] += wav * h1[1]; za[6] += wav * h1[2]; za[7] += wav * h1[3];
                zb[0] += wbv * h0[0]; zb[1] += wbv * h0[1]; zb[2] += wbv * h0[2]; zb[3] += wbv * h0[3];
                zb[4] += wbv * h1[0]; zb[5] += wbv * h1[1]; zb[6] += wbv * h1[2]; zb[7] += wbv * h1[3];
            }
        }
    }
    float wcv = Wc[c];
    float v[NC];
    #pragma unroll
    for (int k = 0; k < NC; ++k) {
        float a = tanhf(za[k]);
        float g = 1.0f / (1.0f + expf(-zb[k]));
        v[k] = a * g * wcv;
    }
    #pragma unroll
    for (int k = 0; k < NC; ++k) {
        float s = v[k];
        #pragma unroll
        for (int off = 32; off > 0; off >>= 1) s += __shfl_down(s, off, 64);
        if (lane == 0) red[k * 4 + wave] = s;
    }
    __syncthreads();
    float logit[NC], m = -1e30f;
    #pragma unroll
    for (int k = 0; k < NC; ++k) {
        logit[k] = red[k * 4] + red[k * 4 + 1] + red[k * 4 + 2] + red[k * 4 + 3] + bc[0];
        m = fmaxf(m, logit[k]);
    }
    float s = 0.0f, ex[NC];
    #pragma unroll
    for (int k = 0; k < NC; ++k) { ex[k] = expf(logit[k] - m); s += ex[k]; }
    float inv = 1.0f / s;
    float o = 0.0f;
    #pragma unroll
    for (int k = 0; k < NC; ++k) o += ex[k] * inv * hpT[c * NC + k];
    out[c] = o;
}

extern "C" void kernel_launch(void* const* d_in, const int* in_sizes, int n_in,
                              void* d_out, int out_size, void* d_ws, size_t ws_size,
                              hipStream_t stream)
{
    (void)in_sizes; (void)n_in; (void)out_size; (void)ws_size;
    const float* x   = (const float*)d_in[0];
    const int*   cid = (const int*)  d_in[1];
    const float* W1  = (const float*)d_in[2];
    const float* b1  = (const float*)d_in[3];
    const float* Wf  = (const float*)d_in[4];
    const float* bfv = (const float*)d_in[5];
    const float* Wa  = (const float*)d_in[6];
    const float* ba  = (const float*)d_in[7];
    const float* Wb  = (const float*)d_in[8];
    const float* bb  = (const float*)d_in[9];
    const float* Wc  = (const float*)d_in[10];
    const float* bc  = (const float*)d_in[11];
    float* out = (float*)d_out;

    // workspace layout (~9.0 MB, no zero-init required anywhere)
    unsigned short* W1b   = (unsigned short*)d_ws;                     // 512 KB
    int*   cnt_partial    = (int*)  ((char*)d_ws + 524288);            // 4 KB
    float* partial        = (float*)((char*)d_ws + 528384);            // 8 MB
    float* stage2         = (float*)((char*)d_ws + 528384 + 8388608);  // 64 KB

    hipLaunchKernelGGL(prep_kernel,   dim3(128),     dim3(256), 0, stream, W1, W1b, cid, cnt_partial);
    hipLaunchKernelGGL(gemm_kernel,   dim3(NN / BM), dim3(256), 0, stream, x, cid, W1b, b1, partial);
    hipLaunchKernelGGL(reduce_kernel, dim3(64),      dim3(256), 0, stream, partial, stage2);
    hipLaunchKernelGGL(head_kernel,   dim3(1),       dim3(256), 0, stream,
                       stage2, cnt_partial, Wf, bfv, Wa, ba, Wb, bb, Wc, bc, out);
}